// Round 1
// baseline (1615.385 us; speedup 1.0000x reference)
//
#include <hip/hip_runtime.h>
#include <math.h>

// GNNBlock: global-LN -> relu*dropout -> SAGE mean-aggr -> dual linear
// N=50000, E=800000, D=128
#define N_NODES 50000
#define N_EDGES 800000
#define D 128
#define EPS 1e-5f

// ---------------- workspace layout ----------------
// [0]      double sum, double sumsq            (16 B)
// [16]     float mean, float rstd              (8 B)
// [64]     int   deg[N]                        (200000 B)
// [200192] float agg[N*D]                      (25.6 MB)  512-aligned
// [25800192] float h[N*D]                      (25.6 MB)  512-aligned
#define WS_STATS_OFF   0
#define WS_MR_OFF      16
#define WS_DEG_OFF     64
#define WS_AGG_OFF     200192
#define WS_H_OFF       25800192
#define WS_ZERO_BYTES  25800192   // stats + mr + deg + agg

// ---------------- kernel 1: global sum / sumsq ----------------
__global__ __launch_bounds__(256) void k_reduce(const float* __restrict__ x,
                                                double* __restrict__ stats,
                                                int total4) {
    int tid = blockIdx.x * blockDim.x + threadIdx.x;
    int stride = gridDim.x * blockDim.x;
    float s = 0.f, ss = 0.f;
    for (int i = tid; i < total4; i += stride) {
        float4 v = ((const float4*)x)[i];
        s  += v.x + v.y + v.z + v.w;
        ss += v.x*v.x + v.y*v.y + v.z*v.z + v.w*v.w;
    }
    // wave (64-lane) reduction
    for (int off = 32; off; off >>= 1) {
        s  += __shfl_down(s, off);
        ss += __shfl_down(ss, off);
    }
    __shared__ float bs[4], bss[4];
    int lane = threadIdx.x & 63, wid = threadIdx.x >> 6;
    if (lane == 0) { bs[wid] = s; bss[wid] = ss; }
    __syncthreads();
    if (threadIdx.x == 0) {
        float t = 0.f, tt = 0.f;
        for (int w = 0; w < 4; ++w) { t += bs[w]; tt += bss[w]; }
        atomicAdd(stats, (double)t);       // ~1024 double atomics total: cheap, exact-ish
        atomicAdd(stats + 1, (double)tt);
    }
}

// ---------------- kernel 2: finalize mean / rstd ----------------
__global__ void k_finalize(const double* __restrict__ stats, float* __restrict__ mr) {
    double M = (double)N_NODES * (double)D;
    double mean = stats[0] / M;
    double var  = stats[1] / M - mean * mean;
    if (var < 0.0) var = 0.0;
    double sd = sqrt(var);
    mr[0] = (float)mean;
    mr[1] = (float)(1.0 / (sd + (double)EPS));
}

// ---------------- kernel 3: h = relu(LN(x)) * mask ----------------
__global__ __launch_bounds__(256) void k_h(const float* __restrict__ x,
                                           const float* __restrict__ mask,
                                           const float* __restrict__ lnw,
                                           const float* __restrict__ lnb,
                                           const float* __restrict__ mr,
                                           float* __restrict__ h,
                                           int total4) {
    float mean = mr[0], rstd = mr[1];
    int tid = blockIdx.x * blockDim.x + threadIdx.x;
    int stride = gridDim.x * blockDim.x;
    for (int i = tid; i < total4; i += stride) {
        float4 v = ((const float4*)x)[i];
        float4 m = ((const float4*)mask)[i];
        int c4 = i & (D / 4 - 1);   // channel float4 index
        float4 w = ((const float4*)lnw)[c4];
        float4 b = ((const float4*)lnb)[c4];
        float4 r;
        r.x = fmaxf((v.x - mean) * rstd * w.x + b.x, 0.f) * m.x;
        r.y = fmaxf((v.y - mean) * rstd * w.y + b.y, 0.f) * m.y;
        r.z = fmaxf((v.z - mean) * rstd * w.z + b.z, 0.f) * m.z;
        r.w = fmaxf((v.w - mean) * rstd * w.w + b.w, 0.f) * m.w;
        ((float4*)h)[i] = r;
    }
}

// ---------------- kernel 4: edge scatter (atomics) ----------------
// 32 lanes per edge, one float4 per lane. 102.4M f32 atomics total.
__global__ __launch_bounds__(256) void k_scatter(const int* __restrict__ ei,
                                                 const float* __restrict__ h,
                                                 float* __restrict__ agg,
                                                 int* __restrict__ deg) {
    long long t = (long long)blockIdx.x * blockDim.x + threadIdx.x;
    int e = (int)(t >> 5);
    if (e >= N_EDGES) return;
    int c = (int)t & 31;
    int src = ei[e];
    int dst = ei[N_EDGES + e];
    float4 v = *(const float4*)(h + (long long)src * D + c * 4);
    float* a = agg + (long long)dst * D + c * 4;
    unsafeAtomicAdd(a + 0, v.x);
    unsafeAtomicAdd(a + 1, v.y);
    unsafeAtomicAdd(a + 2, v.z);
    unsafeAtomicAdd(a + 3, v.w);
    if (c == 0) atomicAdd(deg + dst, 1);
}

// ---------------- kernel 5: tiled matvec vs 128x128 weight ----------------
// FIRST: out = (agg/deg) @ w_l + b_l      SECOND: out += h @ w_r
// block = 256 thr = 32 ch-float4 lanes x 8 node-lanes; 64 nodes/block.
// Weights staged in 64KB LDS; each ds_read_b128 amortized over 4 nodes (16 FMA).
#define FMA4(A, S, W) { A.x += (S)*(W).x; A.y += (S)*(W).y; A.z += (S)*(W).z; A.w += (S)*(W).w; }

template <bool FIRST>
__global__ __launch_bounds__(256) void k_mm(const float* __restrict__ rows,
                                            const float* __restrict__ w,
                                            const float* __restrict__ bias,
                                            const int* __restrict__ deg,
                                            float* __restrict__ out) {
    __shared__ float sw[D * D];   // 64 KB
    for (int i = threadIdx.x; i < D * D / 4; i += blockDim.x)
        ((float4*)sw)[i] = ((const float4*)w)[i];
    __syncthreads();

    int ch4 = threadIdx.x & 31;   // which float4 of the 128 channels
    int g   = threadIdx.x >> 5;   // node-lane 0..7
    int base = blockIdx.x * 64;

    for (int half = 0; half < 2; ++half) {
        int n0 = base + g * 8 + half * 4;   // 4 consecutive nodes
        float4 acc0 = {0,0,0,0}, acc1 = {0,0,0,0}, acc2 = {0,0,0,0}, acc3 = {0,0,0,0};
        const float4* rp0 = (const float4*)(rows + (long long)((n0 + 0) < N_NODES ? (n0 + 0) : 0) * D);
        const float4* rp1 = (const float4*)(rows + (long long)((n0 + 1) < N_NODES ? (n0 + 1) : 0) * D);
        const float4* rp2 = (const float4*)(rows + (long long)((n0 + 2) < N_NODES ? (n0 + 2) : 0) * D);
        const float4* rp3 = (const float4*)(rows + (long long)((n0 + 3) < N_NODES ? (n0 + 3) : 0) * D);

        for (int k0 = 0; k0 < D / 4; ++k0) {
            float4 t0 = rp0[k0], t1 = rp1[k0], t2 = rp2[k0], t3 = rp3[k0];
            float r0[4] = {t0.x, t0.y, t0.z, t0.w};
            float r1[4] = {t1.x, t1.y, t1.z, t1.w};
            float r2[4] = {t2.x, t2.y, t2.z, t2.w};
            float r3[4] = {t3.x, t3.y, t3.z, t3.w};
#pragma unroll
            for (int kk = 0; kk < 4; ++kk) {
                float4 wv = *(const float4*)(sw + (k0 * 4 + kk) * D + ch4 * 4);
                FMA4(acc0, r0[kk], wv);
                FMA4(acc1, r1[kk], wv);
                FMA4(acc2, r2[kk], wv);
                FMA4(acc3, r3[kk], wv);
            }
        }

        float4 accs[4] = {acc0, acc1, acc2, acc3};
#pragma unroll
        for (int j = 0; j < 4; ++j) {
            int n = n0 + j;
            if (n >= N_NODES) continue;
            float* op = out + (long long)n * D + ch4 * 4;
            float4 o;
            if (FIRST) {
                float ds = 1.0f / fmaxf((float)deg[n], 1.0f);
                float4 b = ((const float4*)bias)[ch4];
                o.x = accs[j].x * ds + b.x;
                o.y = accs[j].y * ds + b.y;
                o.z = accs[j].z * ds + b.z;
                o.w = accs[j].w * ds + b.w;
            } else {
                float4 prev = *(float4*)op;
                o.x = prev.x + accs[j].x;
                o.y = prev.y + accs[j].y;
                o.z = prev.z + accs[j].z;
                o.w = prev.w + accs[j].w;
            }
            *(float4*)op = o;
        }
    }
}

// ---------------- launcher ----------------
extern "C" void kernel_launch(void* const* d_in, const int* in_sizes, int n_in,
                              void* d_out, int out_size, void* d_ws, size_t ws_size,
                              hipStream_t stream) {
    const float* x    = (const float*)d_in[0];
    const int*   ei   = (const int*)d_in[1];     // [2,E] int32 per harness convention
    const float* mask = (const float*)d_in[2];
    const float* lnw  = (const float*)d_in[3];
    const float* lnb  = (const float*)d_in[4];
    const float* w_l  = (const float*)d_in[5];
    const float* b_l  = (const float*)d_in[6];
    const float* w_r  = (const float*)d_in[7];
    float* out = (float*)d_out;

    char* ws = (char*)d_ws;
    double* stats = (double*)(ws + WS_STATS_OFF);
    float*  mr    = (float*)(ws + WS_MR_OFF);
    int*    deg   = (int*)(ws + WS_DEG_OFF);
    float*  agg   = (float*)(ws + WS_AGG_OFF);
    float*  h     = (float*)(ws + WS_H_OFF);

    // zero stats + deg + agg (ws is poisoned 0xAA before every launch)
    hipMemsetAsync(d_ws, 0, WS_ZERO_BYTES, stream);

    int total4 = N_NODES * D / 4;   // 1.6M float4s
    k_reduce<<<1024, 256, 0, stream>>>(x, stats, total4);
    k_finalize<<<1, 1, 0, stream>>>(stats, mr);
    k_h<<<2048, 256, 0, stream>>>(x, mask, lnw, lnb, mr, h, total4);

    long long sthreads = (long long)N_EDGES * 32;
    int sblocks = (int)((sthreads + 255) / 256);   // 100000
    k_scatter<<<sblocks, 256, 0, stream>>>(ei, h, agg, deg);

    int mblocks = (N_NODES + 63) / 64;   // 782
    k_mm<true><<<mblocks, 256, 0, stream>>>(agg, w_l, b_l, deg, out);
    k_mm<false><<<mblocks, 256, 0, stream>>>(h, w_r, nullptr, nullptr, out);
}

// Round 2
// 454.910 us; speedup vs baseline: 3.5510x; 3.5510x over previous
//
#include <hip/hip_runtime.h>
#include <math.h>

// GNNBlock: global-LN -> relu*dropout -> SAGE mean-aggr (CSR pull) -> dual linear
// N=50000, E=800000, D=128
#define N_NODES 50000
#define N_EDGES 800000
#define D 128
#define EPS 1e-5f

// ---------------- workspace layout ----------------
// [0]        double sum, double sumsq        (16 B)
// [16]       float mean, float rstd          (8 B)
// [64]       int   deg[N]                    (200000 B)
// [200192]   int   offs[N]                   (200000 B)   exclusive prefix; mutated to "end" by k_fill
// [400448]   int   bucket[E]                 (3.2 MB)     src indices grouped by dst
// [3600640]  float agg[N*D]                  (25.6 MB)    pre-normalized mean aggregation
// [29200896] float h[N*D]                    (25.6 MB)
#define WS_STATS_OFF   0
#define WS_MR_OFF      16
#define WS_DEG_OFF     64
#define WS_OFFS_OFF    200192
#define WS_BUCKET_OFF  400448
#define WS_AGG_OFF     3600640
#define WS_H_OFF       29200896
#define WS_ZERO_BYTES  200192     // stats + mr + deg only

// ---------------- kernel 1: global sum / sumsq ----------------
__global__ __launch_bounds__(256) void k_reduce(const float* __restrict__ x,
                                                double* __restrict__ stats,
                                                int total4) {
    int tid = blockIdx.x * blockDim.x + threadIdx.x;
    int stride = gridDim.x * blockDim.x;
    float s = 0.f, ss = 0.f;
    for (int i = tid; i < total4; i += stride) {
        float4 v = ((const float4*)x)[i];
        s  += v.x + v.y + v.z + v.w;
        ss += v.x*v.x + v.y*v.y + v.z*v.z + v.w*v.w;
    }
    for (int off = 32; off; off >>= 1) {
        s  += __shfl_down(s, off);
        ss += __shfl_down(ss, off);
    }
    __shared__ float bs[4], bss[4];
    int lane = threadIdx.x & 63, wid = threadIdx.x >> 6;
    if (lane == 0) { bs[wid] = s; bss[wid] = ss; }
    __syncthreads();
    if (threadIdx.x == 0) {
        float t = 0.f, tt = 0.f;
        for (int w = 0; w < 4; ++w) { t += bs[w]; tt += bss[w]; }
        atomicAdd(stats, (double)t);
        atomicAdd(stats + 1, (double)tt);
    }
}

// ---------------- kernel 2: finalize mean / rstd ----------------
__global__ void k_finalize(const double* __restrict__ stats, float* __restrict__ mr) {
    double M = (double)N_NODES * (double)D;
    double mean = stats[0] / M;
    double var  = stats[1] / M - mean * mean;
    if (var < 0.0) var = 0.0;
    double sd = sqrt(var);
    mr[0] = (float)mean;
    mr[1] = (float)(1.0 / (sd + (double)EPS));
}

// ---------------- kernel 3: h = relu(LN(x)) * mask ----------------
__global__ __launch_bounds__(256) void k_h(const float* __restrict__ x,
                                           const float* __restrict__ mask,
                                           const float* __restrict__ lnw,
                                           const float* __restrict__ lnb,
                                           const float* __restrict__ mr,
                                           float* __restrict__ h,
                                           int total4) {
    float mean = mr[0], rstd = mr[1];
    int tid = blockIdx.x * blockDim.x + threadIdx.x;
    int stride = gridDim.x * blockDim.x;
    for (int i = tid; i < total4; i += stride) {
        float4 v = ((const float4*)x)[i];
        float4 m = ((const float4*)mask)[i];
        int c4 = i & (D / 4 - 1);
        float4 w = ((const float4*)lnw)[c4];
        float4 b = ((const float4*)lnb)[c4];
        float4 r;
        r.x = fmaxf((v.x - mean) * rstd * w.x + b.x, 0.f) * m.x;
        r.y = fmaxf((v.y - mean) * rstd * w.y + b.y, 0.f) * m.y;
        r.z = fmaxf((v.z - mean) * rstd * w.z + b.z, 0.f) * m.z;
        r.w = fmaxf((v.w - mean) * rstd * w.w + b.w, 0.f) * m.w;
        ((float4*)h)[i] = r;
    }
}

// ---------------- kernel 4a: degree histogram ----------------
__global__ __launch_bounds__(256) void k_deg(const int* __restrict__ ei,
                                             int* __restrict__ deg) {
    int e = blockIdx.x * blockDim.x + threadIdx.x;
    if (e < N_EDGES) atomicAdd(deg + ei[N_EDGES + e], 1);
}

// ---------------- kernel 4b: exclusive prefix sum of deg -> offs ----------------
#define SCAN_T 1024
__global__ __launch_bounds__(SCAN_T) void k_scan(const int* __restrict__ deg,
                                                 int* __restrict__ offs) {
    __shared__ int part[SCAN_T];
    const int CH = (N_NODES + SCAN_T - 1) / SCAN_T;   // 49
    int t = threadIdx.x;
    int begin = t * CH;
    int end = begin + CH; if (end > N_NODES) end = N_NODES;
    int s = 0;
    for (int i = begin; i < end; ++i) s += deg[i];
    part[t] = s;
    __syncthreads();
    for (int off = 1; off < SCAN_T; off <<= 1) {       // inclusive scan
        int v = (t >= off) ? part[t - off] : 0;
        __syncthreads();
        part[t] += v;
        __syncthreads();
    }
    int base = (t == 0) ? 0 : part[t - 1];             // exclusive base for this chunk
    for (int i = begin; i < end; ++i) { offs[i] = base; base += deg[i]; }
}

// ---------------- kernel 4c: fill dst-buckets with src indices ----------------
// mutates offs: afterwards offs[d] == end-of-bucket for d
__global__ __launch_bounds__(256) void k_fill(const int* __restrict__ ei,
                                              int* __restrict__ offs,
                                              int* __restrict__ bucket) {
    int e = blockIdx.x * blockDim.x + threadIdx.x;
    if (e < N_EDGES) {
        int dst = ei[N_EDGES + e];
        int p = atomicAdd(offs + dst, 1);
        bucket[p] = ei[e];
    }
}

// ---------------- kernel 4d: pull aggregation (atomic-free) ----------------
// 32 lanes per dst node, one float4 channel chunk per lane. agg pre-normalized.
__global__ __launch_bounds__(256) void k_agg(const int* __restrict__ bucket,
                                             const int* __restrict__ offs,
                                             const int* __restrict__ deg,
                                             const float* __restrict__ h,
                                             float* __restrict__ agg) {
    int t = blockIdx.x * blockDim.x + threadIdx.x;
    int node = t >> 5;
    if (node >= N_NODES) return;
    int c = t & 31;
    int dg = deg[node];
    int end = offs[node];          // post-fill value = bucket end
    int start = end - dg;
    float4 acc = {0.f, 0.f, 0.f, 0.f};
    for (int j = start; j < end; ++j) {
        int src = bucket[j];
        float4 v = *(const float4*)(h + (long long)src * D + c * 4);
        acc.x += v.x; acc.y += v.y; acc.z += v.z; acc.w += v.w;
    }
    float inv = 1.0f / fmaxf((float)dg, 1.0f);
    float4 o = {acc.x * inv, acc.y * inv, acc.z * inv, acc.w * inv};
    *(float4*)(agg + (long long)node * D + c * 4) = o;
}

// ---------------- kernel 5: tiled matvec vs 128x128 weight ----------------
// FIRST: out = agg @ w_l + b_l      SECOND: out += h @ w_r
#define FMA4(A, S, W) { A.x += (S)*(W).x; A.y += (S)*(W).y; A.z += (S)*(W).z; A.w += (S)*(W).w; }

template <bool FIRST>
__global__ __launch_bounds__(256) void k_mm(const float* __restrict__ rows,
                                            const float* __restrict__ w,
                                            const float* __restrict__ bias,
                                            float* __restrict__ out) {
    __shared__ float sw[D * D];   // 64 KB
    for (int i = threadIdx.x; i < D * D / 4; i += blockDim.x)
        ((float4*)sw)[i] = ((const float4*)w)[i];
    __syncthreads();

    int ch4 = threadIdx.x & 31;
    int g   = threadIdx.x >> 5;
    int base = blockIdx.x * 64;

    for (int half = 0; half < 2; ++half) {
        int n0 = base + g * 8 + half * 4;
        float4 acc0 = {0,0,0,0}, acc1 = {0,0,0,0}, acc2 = {0,0,0,0}, acc3 = {0,0,0,0};
        const float4* rp0 = (const float4*)(rows + (long long)((n0 + 0) < N_NODES ? (n0 + 0) : 0) * D);
        const float4* rp1 = (const float4*)(rows + (long long)((n0 + 1) < N_NODES ? (n0 + 1) : 0) * D);
        const float4* rp2 = (const float4*)(rows + (long long)((n0 + 2) < N_NODES ? (n0 + 2) : 0) * D);
        const float4* rp3 = (const float4*)(rows + (long long)((n0 + 3) < N_NODES ? (n0 + 3) : 0) * D);

        for (int k0 = 0; k0 < D / 4; ++k0) {
            float4 t0 = rp0[k0], t1 = rp1[k0], t2 = rp2[k0], t3 = rp3[k0];
            float r0[4] = {t0.x, t0.y, t0.z, t0.w};
            float r1[4] = {t1.x, t1.y, t1.z, t1.w};
            float r2[4] = {t2.x, t2.y, t2.z, t2.w};
            float r3[4] = {t3.x, t3.y, t3.z, t3.w};
#pragma unroll
            for (int kk = 0; kk < 4; ++kk) {
                float4 wv = *(const float4*)(sw + (k0 * 4 + kk) * D + ch4 * 4);
                FMA4(acc0, r0[kk], wv);
                FMA4(acc1, r1[kk], wv);
                FMA4(acc2, r2[kk], wv);
                FMA4(acc3, r3[kk], wv);
            }
        }

        float4 accs[4] = {acc0, acc1, acc2, acc3};
#pragma unroll
        for (int j = 0; j < 4; ++j) {
            int n = n0 + j;
            if (n >= N_NODES) continue;
            float* op = out + (long long)n * D + ch4 * 4;
            float4 o;
            if (FIRST) {
                float4 b = ((const float4*)bias)[ch4];
                o.x = accs[j].x + b.x;
                o.y = accs[j].y + b.y;
                o.z = accs[j].z + b.z;
                o.w = accs[j].w + b.w;
            } else {
                float4 prev = *(float4*)op;
                o.x = prev.x + accs[j].x;
                o.y = prev.y + accs[j].y;
                o.z = prev.z + accs[j].z;
                o.w = prev.w + accs[j].w;
            }
            *(float4*)op = o;
        }
    }
}

// ---------------- launcher ----------------
extern "C" void kernel_launch(void* const* d_in, const int* in_sizes, int n_in,
                              void* d_out, int out_size, void* d_ws, size_t ws_size,
                              hipStream_t stream) {
    const float* x    = (const float*)d_in[0];
    const int*   ei   = (const int*)d_in[1];
    const float* mask = (const float*)d_in[2];
    const float* lnw  = (const float*)d_in[3];
    const float* lnb  = (const float*)d_in[4];
    const float* w_l  = (const float*)d_in[5];
    const float* b_l  = (const float*)d_in[6];
    const float* w_r  = (const float*)d_in[7];
    float* out = (float*)d_out;

    char* ws = (char*)d_ws;
    double* stats = (double*)(ws + WS_STATS_OFF);
    float*  mr    = (float*)(ws + WS_MR_OFF);
    int*    deg   = (int*)(ws + WS_DEG_OFF);
    int*    offs  = (int*)(ws + WS_OFFS_OFF);
    int*    bucket= (int*)(ws + WS_BUCKET_OFF);
    float*  agg   = (float*)(ws + WS_AGG_OFF);
    float*  h     = (float*)(ws + WS_H_OFF);

    // zero stats + mr + deg (ws is poisoned 0xAA before every launch)
    hipMemsetAsync(d_ws, 0, WS_ZERO_BYTES, stream);

    int total4 = N_NODES * D / 4;
    k_reduce<<<1024, 256, 0, stream>>>(x, stats, total4);
    k_finalize<<<1, 1, 0, stream>>>(stats, mr);
    k_h<<<2048, 256, 0, stream>>>(x, mask, lnw, lnb, mr, h, total4);

    int eblocks = (N_EDGES + 255) / 256;   // 3125
    k_deg<<<eblocks, 256, 0, stream>>>(ei, deg);
    k_scan<<<1, SCAN_T, 0, stream>>>(deg, offs);
    k_fill<<<eblocks, 256, 0, stream>>>(ei, offs, bucket);

    int ablocks = (N_NODES * 32 + 255) / 256;   // 6250
    k_agg<<<ablocks, 256, 0, stream>>>(bucket, offs, deg, h, agg);

    int mblocks = (N_NODES + 63) / 64;   // 782
    k_mm<true><<<mblocks, 256, 0, stream>>>(agg, w_l, b_l, out);
    k_mm<false><<<mblocks, 256, 0, stream>>>(h, w_r, nullptr, out);
}

// Round 5
// 362.352 us; speedup vs baseline: 4.4581x; 1.2554x over previous
//
#include <hip/hip_runtime.h>
#include <math.h>

// GNNBlock: global-LN -> relu*dropout -> SAGE mean-aggr (CSR pull) -> fused dual linear
// N=50000, E=800000, D=128
#define N_NODES 50000
#define N_EDGES 800000
#define D 128
#define EPS 1e-5f

// ---------------- workspace layout ----------------
// [0]        double sum, double sumsq        (16 B)
// [16]       int cursor                      (4 B)
// [64]       int   deg[N]                    (200000 B)
// [200192]   int   offs[N]                   (200000 B)   start; mutated to "end" by fill
// [400448]   int   bucket[E]                 (3.2 MB)     src indices grouped by dst
// [3600640]  float agg[N*D]                  (25.6 MB)    pre-normalized mean aggregation
// [29200896] float h[N*D]                    (25.6 MB)
#define WS_STATS_OFF   0
#define WS_CUR_OFF     16
#define WS_DEG_OFF     64
#define WS_OFFS_OFF    200192
#define WS_BUCKET_OFF  400448
#define WS_AGG_OFF     3600640
#define WS_H_OFF       29200896
#define WS_ZERO_BYTES  200192     // stats + cursor + deg

#define RED_BLOCKS 1024
#define DEG_BLOCKS ((N_EDGES + 255) / 256)   // 3125
#define H_BLOCKS   2048
#define FILL_BLOCKS DEG_BLOCKS

// ---------------- kernel 1: global sum/sumsq + degree histogram (fused, independent) ----------------
__global__ __launch_bounds__(256) void k_pre(const float* __restrict__ x,
                                             const int* __restrict__ ei,
                                             double* __restrict__ stats,
                                             int* __restrict__ deg,
                                             int total4) {
    __shared__ float bs[4], bss[4];
    if (blockIdx.x < RED_BLOCKS) {
        int tid = blockIdx.x * 256 + threadIdx.x;
        int stride = RED_BLOCKS * 256;
        float s = 0.f, ss = 0.f;
        for (int i = tid; i < total4; i += stride) {
            float4 v = ((const float4*)x)[i];
            s  += v.x + v.y + v.z + v.w;
            ss += v.x*v.x + v.y*v.y + v.z*v.z + v.w*v.w;
        }
        for (int off = 32; off; off >>= 1) {
            s  += __shfl_down(s, off);
            ss += __shfl_down(ss, off);
        }
        int lane = threadIdx.x & 63, wid = threadIdx.x >> 6;
        if (lane == 0) { bs[wid] = s; bss[wid] = ss; }
        __syncthreads();
        if (threadIdx.x == 0) {
            float t = 0.f, tt = 0.f;
            for (int w = 0; w < 4; ++w) { t += bs[w]; tt += bss[w]; }
            atomicAdd(stats, (double)t);
            atomicAdd(stats + 1, (double)tt);
        }
    } else {
        int e = (blockIdx.x - RED_BLOCKS) * 256 + threadIdx.x;
        if (e < N_EDGES) atomicAdd(deg + ei[N_EDGES + e], 1);
    }
}

// ---------------- kernel 2: bucket-region assignment (block scan + global cursor) ----------------
// Region order across blocks is non-deterministic (atomic) but each node gets a
// valid contiguous [offs, offs+deg) slice — sufficient for grouping by dst.
__global__ __launch_bounds__(256) void k_offs(const int* __restrict__ deg,
                                              int* __restrict__ offs,
                                              int* __restrict__ cursor) {
    __shared__ int sc[256];
    __shared__ int sbase;
    int t = threadIdx.x;
    int n = blockIdx.x * 256 + t;
    int d = (n < N_NODES) ? deg[n] : 0;
    sc[t] = d;
    __syncthreads();
    for (int off = 1; off < 256; off <<= 1) {   // inclusive Hillis-Steele scan
        int u = (t >= off) ? sc[t - off] : 0;
        __syncthreads();
        sc[t] += u;
        __syncthreads();
    }
    int incl = sc[t];
    if (t == 255) sbase = atomicAdd(cursor, incl);
    __syncthreads();
    if (n < N_NODES) offs[n] = sbase + (incl - d);
}

// ---------------- kernel 3: h = relu(LN(x))*mask  +  bucket fill (fused, independent) ----------------
__global__ __launch_bounds__(256) void k_hfill(const float* __restrict__ x,
                                               const float* __restrict__ mask,
                                               const float* __restrict__ lnw,
                                               const float* __restrict__ lnb,
                                               const double* __restrict__ stats,
                                               const int* __restrict__ ei,
                                               int* __restrict__ offs,
                                               int* __restrict__ bucket,
                                               float* __restrict__ h,
                                               int total4) {
    if (blockIdx.x < H_BLOCKS) {
        double M = (double)N_NODES * (double)D;
        double mean_d = stats[0] / M;
        double var = stats[1] / M - mean_d * mean_d;
        if (var < 0.0) var = 0.0;
        float mean = (float)mean_d;
        float rstd = (float)(1.0 / (sqrt(var) + (double)EPS));
        int tid = blockIdx.x * 256 + threadIdx.x;
        int stride = H_BLOCKS * 256;
        for (int i = tid; i < total4; i += stride) {
            float4 v = ((const float4*)x)[i];
            float4 m = ((const float4*)mask)[i];
            int c4 = i & (D / 4 - 1);
            float4 w = ((const float4*)lnw)[c4];
            float4 b = ((const float4*)lnb)[c4];
            float4 r;
            r.x = fmaxf((v.x - mean) * rstd * w.x + b.x, 0.f) * m.x;
            r.y = fmaxf((v.y - mean) * rstd * w.y + b.y, 0.f) * m.y;
            r.z = fmaxf((v.z - mean) * rstd * w.z + b.z, 0.f) * m.z;
            r.w = fmaxf((v.w - mean) * rstd * w.w + b.w, 0.f) * m.w;
            ((float4*)h)[i] = r;
        }
    } else {
        int e = (blockIdx.x - H_BLOCKS) * 256 + threadIdx.x;
        if (e < N_EDGES) {
            int dst = ei[N_EDGES + e];
            int p = atomicAdd(offs + dst, 1);
            bucket[p] = ei[e];
        }
    }
}

// ---------------- kernel 4: pull aggregation (atomic-free) ----------------
// 32 lanes per dst node, one float4 channel chunk per lane. agg pre-normalized.
__global__ __launch_bounds__(256) void k_agg(const int* __restrict__ bucket,
                                             const int* __restrict__ offs,
                                             const int* __restrict__ deg,
                                             const float* __restrict__ h,
                                             float* __restrict__ agg) {
    int t = blockIdx.x * blockDim.x + threadIdx.x;
    int node = t >> 5;
    if (node >= N_NODES) return;
    int c = t & 31;
    int dg = deg[node];
    int end = offs[node];          // post-fill value = bucket end
    int start = end - dg;
    float4 acc = {0.f, 0.f, 0.f, 0.f};
    for (int j = start; j < end; ++j) {
        int src = bucket[j];
        float4 v = *(const float4*)(h + (long long)src * D + c * 4);
        acc.x += v.x; acc.y += v.y; acc.z += v.z; acc.w += v.w;
    }
    float inv = 1.0f / fmaxf((float)dg, 1.0f);
    float4 o = {acc.x * inv, acc.y * inv, acc.z * inv, acc.w * inv};
    *(float4*)(agg + (long long)node * D + c * 4) = o;
}

// ---------------- kernel 5: fused dual matvec: out = agg@w_l + b_l + h@w_r ----------------
// 256 thr = 8 node-groups x 32 ch4-lanes; 64 nodes/block. One 64KB LDS weight
// buffer staged twice (w_l phase, then w_r phase); accumulators persist.
#define FMA4(A, S, W) { A.x += (S)*(W).x; A.y += (S)*(W).y; A.z += (S)*(W).z; A.w += (S)*(W).w; }

__global__ __launch_bounds__(256) void k_mmf(const float* __restrict__ agg,
                                             const float* __restrict__ h,
                                             const float* __restrict__ w_l,
                                             const float* __restrict__ w_r,
                                             const float* __restrict__ b_l,
                                             float* __restrict__ out) {
    __shared__ float sw[D * D];   // 64 KB
    int ch4 = threadIdx.x & 31;
    int g   = threadIdx.x >> 5;
    int base = blockIdx.x * 64;

    float4 acc[8];   // [half*4 + j], statically indexed after unroll
#pragma unroll
    for (int i = 0; i < 8; ++i) acc[i] = {0.f, 0.f, 0.f, 0.f};

    float4 bl = ((const float4*)b_l)[ch4];

#pragma unroll
    for (int phase = 0; phase < 2; ++phase) {
        const float* wsrc = phase == 0 ? w_l : w_r;
        const float* rows = phase == 0 ? agg : h;
        if (phase) __syncthreads();   // protect sw reuse
        for (int i = threadIdx.x; i < D * D / 4; i += 256)
            ((float4*)sw)[i] = ((const float4*)wsrc)[i];
        __syncthreads();

#pragma unroll
        for (int half = 0; half < 2; ++half) {
            int n0 = base + g * 8 + half * 4;
            const float4* rp0 = (const float4*)(rows + (long long)((n0 + 0) < N_NODES ? (n0 + 0) : 0) * D);
            const float4* rp1 = (const float4*)(rows + (long long)((n0 + 1) < N_NODES ? (n0 + 1) : 0) * D);
            const float4* rp2 = (const float4*)(rows + (long long)((n0 + 2) < N_NODES ? (n0 + 2) : 0) * D);
            const float4* rp3 = (const float4*)(rows + (long long)((n0 + 3) < N_NODES ? (n0 + 3) : 0) * D);

            for (int k0 = 0; k0 < D / 4; ++k0) {
                float4 t0 = rp0[k0], t1 = rp1[k0], t2 = rp2[k0], t3 = rp3[k0];
                float r0[4] = {t0.x, t0.y, t0.z, t0.w};
                float r1[4] = {t1.x, t1.y, t1.z, t1.w};
                float r2[4] = {t2.x, t2.y, t2.z, t2.w};
                float r3[4] = {t3.x, t3.y, t3.z, t3.w};
#pragma unroll
                for (int kk = 0; kk < 4; ++kk) {
                    float4 wv = *(const float4*)(sw + (k0 * 4 + kk) * D + ch4 * 4);
                    FMA4(acc[half * 4 + 0], r0[kk], wv);
                    FMA4(acc[half * 4 + 1], r1[kk], wv);
                    FMA4(acc[half * 4 + 2], r2[kk], wv);
                    FMA4(acc[half * 4 + 3], r3[kk], wv);
                }
            }
        }
    }

#pragma unroll
    for (int half = 0; half < 2; ++half) {
#pragma unroll
        for (int j = 0; j < 4; ++j) {
            int n = base + g * 8 + half * 4 + j;
            if (n < N_NODES) {
                float4 a = acc[half * 4 + j];
                float4 o = {a.x + bl.x, a.y + bl.y, a.z + bl.z, a.w + bl.w};
                *(float4*)(out + (long long)n * D + ch4 * 4) = o;
            }
        }
    }
}

// ---------------- launcher ----------------
extern "C" void kernel_launch(void* const* d_in, const int* in_sizes, int n_in,
                              void* d_out, int out_size, void* d_ws, size_t ws_size,
                              hipStream_t stream) {
    const float* x    = (const float*)d_in[0];
    const int*   ei   = (const int*)d_in[1];
    const float* mask = (const float*)d_in[2];
    const float* lnw  = (const float*)d_in[3];
    const float* lnb  = (const float*)d_in[4];
    const float* w_l  = (const float*)d_in[5];
    const float* b_l  = (const float*)d_in[6];
    const float* w_r  = (const float*)d_in[7];
    float* out = (float*)d_out;

    char* ws = (char*)d_ws;
    double* stats = (double*)(ws + WS_STATS_OFF);
    int*    cursor= (int*)(ws + WS_CUR_OFF);
    int*    deg   = (int*)(ws + WS_DEG_OFF);
    int*    offs  = (int*)(ws + WS_OFFS_OFF);
    int*    bucket= (int*)(ws + WS_BUCKET_OFF);
    float*  agg   = (float*)(ws + WS_AGG_OFF);
    float*  h     = (float*)(ws + WS_H_OFF);

    // zero stats + cursor + deg (ws is poisoned 0xAA before every launch)
    hipMemsetAsync(d_ws, 0, WS_ZERO_BYTES, stream);

    int total4 = N_NODES * D / 4;
    k_pre<<<RED_BLOCKS + DEG_BLOCKS, 256, 0, stream>>>(x, ei, stats, deg, total4);
    k_offs<<<(N_NODES + 255) / 256, 256, 0, stream>>>(deg, offs, cursor);
    k_hfill<<<H_BLOCKS + FILL_BLOCKS, 256, 0, stream>>>(x, mask, lnw, lnb, stats,
                                                        ei, offs, bucket, h, total4);
    int ablocks = (N_NODES * 32 + 255) / 256;   // 6250
    k_agg<<<ablocks, 256, 0, stream>>>(bucket, offs, deg, h, agg);
    int mblocks = (N_NODES + 63) / 64;          // 782
    k_mmf<<<mblocks, 256, 0, stream>>>(agg, h, w_l, w_r, b_l, out);
}

// Round 6
// 345.942 us; speedup vs baseline: 4.6695x; 1.0474x over previous
//
#include <hip/hip_runtime.h>
#include <math.h>

// GNNBlock: global-LN -> relu*dropout -> SAGE mean-aggr (CSR pull) -> fused dual linear
// N=50000, E=800000, D=128
#define N_NODES 50000
#define N_EDGES 800000
#define D 128
#define EPS 1e-5f

// ---------------- workspace layout ----------------
// [0]        double sum, double sumsq        (16 B)
// [16]       int cursor                      (4 B)
// [64]       int   deg[N]                    (200000 B)
// [200192]   int   offs[N]                   (200000 B)   start; mutated to "end" by fill
// [400448]   int   bucket[E]                 (3.2 MB)     src indices grouped by dst
// [3600640]  float agg[N*D]                  (25.6 MB)    pre-normalized mean aggregation
// [29200896] float h[N*D]                    (25.6 MB)
#define WS_STATS_OFF   0
#define WS_CUR_OFF     16
#define WS_DEG_OFF     64
#define WS_OFFS_OFF    200192
#define WS_BUCKET_OFF  400448
#define WS_AGG_OFF     3600640
#define WS_H_OFF       29200896
#define WS_ZERO_BYTES  200192     // stats + cursor + deg

#define RED_BLOCKS 1024
#define DEG_BLOCKS ((N_EDGES + 255) / 256)   // 3125
#define H_BLOCKS   2048
#define FILL_BLOCKS DEG_BLOCKS

// ---------------- kernel 1: global sum/sumsq + degree histogram (fused, independent) ----------------
__global__ __launch_bounds__(256) void k_pre(const float* __restrict__ x,
                                             const int* __restrict__ ei,
                                             double* __restrict__ stats,
                                             int* __restrict__ deg,
                                             int total4) {
    __shared__ float bs[4], bss[4];
    if (blockIdx.x < RED_BLOCKS) {
        int tid = blockIdx.x * 256 + threadIdx.x;
        int stride = RED_BLOCKS * 256;
        float s = 0.f, ss = 0.f;
        for (int i = tid; i < total4; i += stride) {
            float4 v = ((const float4*)x)[i];
            s  += v.x + v.y + v.z + v.w;
            ss += v.x*v.x + v.y*v.y + v.z*v.z + v.w*v.w;
        }
        for (int off = 32; off; off >>= 1) {
            s  += __shfl_down(s, off);
            ss += __shfl_down(ss, off);
        }
        int lane = threadIdx.x & 63, wid = threadIdx.x >> 6;
        if (lane == 0) { bs[wid] = s; bss[wid] = ss; }
        __syncthreads();
        if (threadIdx.x == 0) {
            float t = 0.f, tt = 0.f;
            for (int w = 0; w < 4; ++w) { t += bs[w]; tt += bss[w]; }
            atomicAdd(stats, (double)t);
            atomicAdd(stats + 1, (double)tt);
        }
    } else {
        int e = (blockIdx.x - RED_BLOCKS) * 256 + threadIdx.x;
        if (e < N_EDGES) atomicAdd(deg + ei[N_EDGES + e], 1);
    }
}

// ---------------- kernel 2: bucket-region assignment (block scan + global cursor) ----------------
// Region order across blocks is non-deterministic (atomic) but each node gets a
// valid contiguous [offs, offs+deg) slice — sufficient for grouping by dst.
__global__ __launch_bounds__(256) void k_offs(const int* __restrict__ deg,
                                              int* __restrict__ offs,
                                              int* __restrict__ cursor) {
    __shared__ int sc[256];
    __shared__ int sbase;
    int t = threadIdx.x;
    int n = blockIdx.x * 256 + t;
    int d = (n < N_NODES) ? deg[n] : 0;
    sc[t] = d;
    __syncthreads();
    for (int off = 1; off < 256; off <<= 1) {   // inclusive Hillis-Steele scan
        int u = (t >= off) ? sc[t - off] : 0;
        __syncthreads();
        sc[t] += u;
        __syncthreads();
    }
    int incl = sc[t];
    if (t == 255) sbase = atomicAdd(cursor, incl);
    __syncthreads();
    if (n < N_NODES) offs[n] = sbase + (incl - d);
}

// ---------------- kernel 3: h = relu(LN(x))*mask  +  bucket fill (fused, independent) ----------------
__global__ __launch_bounds__(256) void k_hfill(const float* __restrict__ x,
                                               const float* __restrict__ mask,
                                               const float* __restrict__ lnw,
                                               const float* __restrict__ lnb,
                                               const double* __restrict__ stats,
                                               const int* __restrict__ ei,
                                               int* __restrict__ offs,
                                               int* __restrict__ bucket,
                                               float* __restrict__ h,
                                               int total4) {
    if (blockIdx.x < H_BLOCKS) {
        double M = (double)N_NODES * (double)D;
        double mean_d = stats[0] / M;
        double var = stats[1] / M - mean_d * mean_d;
        if (var < 0.0) var = 0.0;
        float mean = (float)mean_d;
        float rstd = (float)(1.0 / (sqrt(var) + (double)EPS));
        int tid = blockIdx.x * 256 + threadIdx.x;
        int stride = H_BLOCKS * 256;
        for (int i = tid; i < total4; i += stride) {
            float4 v = ((const float4*)x)[i];
            float4 m = ((const float4*)mask)[i];
            int c4 = i & (D / 4 - 1);
            float4 w = ((const float4*)lnw)[c4];
            float4 b = ((const float4*)lnb)[c4];
            float4 r;
            r.x = fmaxf((v.x - mean) * rstd * w.x + b.x, 0.f) * m.x;
            r.y = fmaxf((v.y - mean) * rstd * w.y + b.y, 0.f) * m.y;
            r.z = fmaxf((v.z - mean) * rstd * w.z + b.z, 0.f) * m.z;
            r.w = fmaxf((v.w - mean) * rstd * w.w + b.w, 0.f) * m.w;
            ((float4*)h)[i] = r;
        }
    } else {
        int e = (blockIdx.x - H_BLOCKS) * 256 + threadIdx.x;
        if (e < N_EDGES) {
            int dst = ei[N_EDGES + e];
            int p = atomicAdd(offs + dst, 1);
            bucket[p] = ei[e];
        }
    }
}

// ---------------- kernel 4: pull aggregation (atomic-free) ----------------
// 32 lanes per dst node, one float4 channel chunk per lane. agg pre-normalized.
__global__ __launch_bounds__(256) void k_agg(const int* __restrict__ bucket,
                                             const int* __restrict__ offs,
                                             const int* __restrict__ deg,
                                             const float* __restrict__ h,
                                             float* __restrict__ agg) {
    int t = blockIdx.x * blockDim.x + threadIdx.x;
    int node = t >> 5;
    if (node >= N_NODES) return;
    int c = t & 31;
    int dg = deg[node];
    int end = offs[node];          // post-fill value = bucket end
    int start = end - dg;
    float4 acc = {0.f, 0.f, 0.f, 0.f};
    for (int j = start; j < end; ++j) {
        int src = bucket[j];
        float4 v = *(const float4*)(h + (long long)src * D + c * 4);
        acc.x += v.x; acc.y += v.y; acc.z += v.z; acc.w += v.w;
    }
    float inv = 1.0f / fmaxf((float)dg, 1.0f);
    float4 o = {acc.x * inv, acc.y * inv, acc.z * inv, acc.w * inv};
    *(float4*)(agg + (long long)node * D + c * 4) = o;
}

// ---------------- kernel 5: fused dual matvec: out = agg@w_l + b_l + h@w_r ----------------
// 256 thr = 8 node-groups x 32 ch4-lanes; 64 nodes/block, 8 rows/thread.
// Weight staged in 32KB LDS chunks (64 K-rows), 4 stages total (2 phases x 2 chunks).
// Each ds_read_b128 of a weight float4 feeds 8 FMA4s (was 4) -> half the LDS
// traffic per FLOP. LDS 32KB + launch_bounds(256,4) -> 4 blocks/CU (~50% occ,
// was 16% at 64KB/2 blocks).
#define FMA4(A, S, W) { A.x += (S)*(W).x; A.y += (S)*(W).y; A.z += (S)*(W).z; A.w += (S)*(W).w; }

__global__ __launch_bounds__(256, 4) void k_mmf(const float* __restrict__ agg,
                                                const float* __restrict__ h,
                                                const float* __restrict__ w_l,
                                                const float* __restrict__ w_r,
                                                const float* __restrict__ b_l,
                                                float* __restrict__ out) {
    __shared__ float sw[64 * D];             // 32 KB: 64 K-rows of the weight
    float4* sw4 = (float4*)sw;
    int ch4 = threadIdx.x & 31;              // output-channel float4 lane
    int g   = threadIdx.x >> 5;              // node group 0..7
    int n0  = blockIdx.x * 64 + g * 8;       // 8 consecutive rows per thread
    int n0c = (n0 <= N_NODES - 8) ? n0 : (N_NODES - 8);   // N%8==0 -> no partial groups

    float4 acc[8];
#pragma unroll
    for (int j = 0; j < 8; ++j) acc[j] = {0.f, 0.f, 0.f, 0.f};

#pragma unroll
    for (int phase = 0; phase < 2; ++phase) {
        const float4* wsrc4 = (const float4*)(phase == 0 ? w_l : w_r);
        const float4* rp4   = (const float4*)((phase == 0 ? agg : h) + (long long)n0c * D);
#pragma unroll
        for (int chunk = 0; chunk < 2; ++chunk) {
            if (phase | chunk) __syncthreads();      // wait for prev consumers
            // stage 64 weight rows (32 KB), coalesced
#pragma unroll
            for (int i = 0; i < 8; ++i)
                sw4[i * 256 + threadIdx.x] = wsrc4[chunk * 2048 + i * 256 + threadIdx.x];
            __syncthreads();

            for (int k0 = 0; k0 < 16; ++k0) {
                float4 r[8];
#pragma unroll
                for (int j = 0; j < 8; ++j)
                    r[j] = rp4[(j << 5) + chunk * 16 + k0];
#pragma unroll
                for (int kk = 0; kk < 4; ++kk) {
                    float4 wv = sw4[(k0 * 4 + kk) * 32 + ch4];
#pragma unroll
                    for (int j = 0; j < 8; ++j) {
                        float rj[4] = {r[j].x, r[j].y, r[j].z, r[j].w};
                        FMA4(acc[j], rj[kk], wv);
                    }
                }
            }
        }
    }

    float4 bl = ((const float4*)b_l)[ch4];
#pragma unroll
    for (int j = 0; j < 8; ++j) {
        int n = n0 + j;
        if (n < N_NODES) {
            float4 o = {acc[j].x + bl.x, acc[j].y + bl.y, acc[j].z + bl.z, acc[j].w + bl.w};
            *(float4*)(out + (long long)n * D + ch4 * 4) = o;
        }
    }
}

// ---------------- launcher ----------------
extern "C" void kernel_launch(void* const* d_in, const int* in_sizes, int n_in,
                              void* d_out, int out_size, void* d_ws, size_t ws_size,
                              hipStream_t stream) {
    const float* x    = (const float*)d_in[0];
    const int*   ei   = (const int*)d_in[1];
    const float* mask = (const float*)d_in[2];
    const float* lnw  = (const float*)d_in[3];
    const float* lnb  = (const float*)d_in[4];
    const float* w_l  = (const float*)d_in[5];
    const float* b_l  = (const float*)d_in[6];
    const float* w_r  = (const float*)d_in[7];
    float* out = (float*)d_out;

    char* ws = (char*)d_ws;
    double* stats = (double*)(ws + WS_STATS_OFF);
    int*    cursor= (int*)(ws + WS_CUR_OFF);
    int*    deg   = (int*)(ws + WS_DEG_OFF);
    int*    offs  = (int*)(ws + WS_OFFS_OFF);
    int*    bucket= (int*)(ws + WS_BUCKET_OFF);
    float*  agg   = (float*)(ws + WS_AGG_OFF);
    float*  h     = (float*)(ws + WS_H_OFF);

    // zero stats + cursor + deg (ws is poisoned 0xAA before every launch)
    hipMemsetAsync(d_ws, 0, WS_ZERO_BYTES, stream);

    int total4 = N_NODES * D / 4;
    k_pre<<<RED_BLOCKS + DEG_BLOCKS, 256, 0, stream>>>(x, ei, stats, deg, total4);
    k_offs<<<(N_NODES + 255) / 256, 256, 0, stream>>>(deg, offs, cursor);
    k_hfill<<<H_BLOCKS + FILL_BLOCKS, 256, 0, stream>>>(x, mask, lnw, lnb, stats,
                                                        ei, offs, bucket, h, total4);
    int ablocks = (N_NODES * 32 + 255) / 256;   // 6250
    k_agg<<<ablocks, 256, 0, stream>>>(bucket, offs, deg, h, agg);
    int mblocks = (N_NODES + 63) / 64;          // 782
    k_mmf<<<mblocks, 256, 0, stream>>>(agg, h, w_l, w_r, b_l, out);
}

// Round 7
// 340.518 us; speedup vs baseline: 4.7439x; 1.0159x over previous
//
#include <hip/hip_runtime.h>
#include <math.h>

// GNNBlock: global-LN -> relu*dropout -> SAGE mean-aggr (CSR pull, bf16 gather) -> fused dual linear
// N=50000, E=800000, D=128
#define N_NODES 50000
#define N_EDGES 800000
#define D 128
#define EPS 1e-5f

// ---------------- workspace layout ----------------
// [0]        double sum, double sumsq        (16 B)
// [16]       int cursor                      (4 B)
// [64]       int   deg[N]                    (200000 B)
// [200192]   int   offs[N]                   (200000 B)   start; mutated to "end" by fill
// [400448]   int   bucket[E]                 (3.2 MB)     src indices grouped by dst
// [3600640]  float agg[N*D]                  (25.6 MB)    pre-normalized mean aggregation (f32)
// [29200896] ushort h16[N*D]                 (12.8 MB)    h = relu(LN(x))*mask, bf16 (RNE)
#define WS_STATS_OFF   0
#define WS_CUR_OFF     16
#define WS_DEG_OFF     64
#define WS_OFFS_OFF    200192
#define WS_BUCKET_OFF  400448
#define WS_AGG_OFF     3600640
#define WS_H_OFF       29200896
#define WS_ZERO_BYTES  200192     // stats + cursor + deg

#define RED_BLOCKS 1024
#define DEG_BLOCKS ((N_EDGES + 255) / 256)   // 3125
#define H_BLOCKS   2048
#define FILL_BLOCKS DEG_BLOCKS

// bf16 helpers (RNE encode, shift decode)
static __device__ inline unsigned short f2bf(float f) {
    unsigned u = __float_as_uint(f);
    return (unsigned short)((u + 0x7FFFu + ((u >> 16) & 1u)) >> 16);
}

// ---------------- kernel 1: global sum/sumsq + degree histogram (fused, independent) ----------------
__global__ __launch_bounds__(256) void k_pre(const float* __restrict__ x,
                                             const int* __restrict__ ei,
                                             double* __restrict__ stats,
                                             int* __restrict__ deg,
                                             int total4) {
    __shared__ float bs[4], bss[4];
    if (blockIdx.x < RED_BLOCKS) {
        int tid = blockIdx.x * 256 + threadIdx.x;
        int stride = RED_BLOCKS * 256;
        float s = 0.f, ss = 0.f;
        for (int i = tid; i < total4; i += stride) {
            float4 v = ((const float4*)x)[i];
            s  += v.x + v.y + v.z + v.w;
            ss += v.x*v.x + v.y*v.y + v.z*v.z + v.w*v.w;
        }
        for (int off = 32; off; off >>= 1) {
            s  += __shfl_down(s, off);
            ss += __shfl_down(ss, off);
        }
        int lane = threadIdx.x & 63, wid = threadIdx.x >> 6;
        if (lane == 0) { bs[wid] = s; bss[wid] = ss; }
        __syncthreads();
        if (threadIdx.x == 0) {
            float t = 0.f, tt = 0.f;
            for (int w = 0; w < 4; ++w) { t += bs[w]; tt += bss[w]; }
            atomicAdd(stats, (double)t);
            atomicAdd(stats + 1, (double)tt);
        }
    } else {
        int e = (blockIdx.x - RED_BLOCKS) * 256 + threadIdx.x;
        if (e < N_EDGES) atomicAdd(deg + ei[N_EDGES + e], 1);
    }
}

// ---------------- kernel 2: bucket-region assignment (block scan + global cursor) ----------------
__global__ __launch_bounds__(256) void k_offs(const int* __restrict__ deg,
                                              int* __restrict__ offs,
                                              int* __restrict__ cursor) {
    __shared__ int sc[256];
    __shared__ int sbase;
    int t = threadIdx.x;
    int n = blockIdx.x * 256 + t;
    int d = (n < N_NODES) ? deg[n] : 0;
    sc[t] = d;
    __syncthreads();
    for (int off = 1; off < 256; off <<= 1) {   // inclusive Hillis-Steele scan
        int u = (t >= off) ? sc[t - off] : 0;
        __syncthreads();
        sc[t] += u;
        __syncthreads();
    }
    int incl = sc[t];
    if (t == 255) sbase = atomicAdd(cursor, incl);
    __syncthreads();
    if (n < N_NODES) offs[n] = sbase + (incl - d);
}

// ---------------- kernel 3: h16 = bf16(relu(LN(x))*mask)  +  bucket fill (fused) ----------------
__global__ __launch_bounds__(256) void k_hfill(const float* __restrict__ x,
                                               const float* __restrict__ mask,
                                               const float* __restrict__ lnw,
                                               const float* __restrict__ lnb,
                                               const double* __restrict__ stats,
                                               const int* __restrict__ ei,
                                               int* __restrict__ offs,
                                               int* __restrict__ bucket,
                                               unsigned short* __restrict__ h16,
                                               int total4) {
    if (blockIdx.x < H_BLOCKS) {
        double M = (double)N_NODES * (double)D;
        double mean_d = stats[0] / M;
        double var = stats[1] / M - mean_d * mean_d;
        if (var < 0.0) var = 0.0;
        float mean = (float)mean_d;
        float rstd = (float)(1.0 / (sqrt(var) + (double)EPS));
        int tid = blockIdx.x * 256 + threadIdx.x;
        int stride = H_BLOCKS * 256;
        for (int i = tid; i < total4; i += stride) {
            float4 v = ((const float4*)x)[i];
            float4 m = ((const float4*)mask)[i];
            int c4 = i & (D / 4 - 1);
            float4 w = ((const float4*)lnw)[c4];
            float4 b = ((const float4*)lnb)[c4];
            float4 r;
            r.x = fmaxf((v.x - mean) * rstd * w.x + b.x, 0.f) * m.x;
            r.y = fmaxf((v.y - mean) * rstd * w.y + b.y, 0.f) * m.y;
            r.z = fmaxf((v.z - mean) * rstd * w.z + b.z, 0.f) * m.z;
            r.w = fmaxf((v.w - mean) * rstd * w.w + b.w, 0.f) * m.w;
            ushort4 o;
            o.x = f2bf(r.x); o.y = f2bf(r.y); o.z = f2bf(r.z); o.w = f2bf(r.w);
            ((ushort4*)h16)[i] = o;
        }
    } else {
        int e = (blockIdx.x - H_BLOCKS) * 256 + threadIdx.x;
        if (e < N_EDGES) {
            int dst = ei[N_EDGES + e];
            int p = atomicAdd(offs + dst, 1);
            bucket[p] = ei[e];
        }
    }
}

// ---------------- kernel 4: pull aggregation (atomic-free, bf16 gather) ----------------
// 32 lanes per dst node, 4 bf16 channels (8B) per lane. agg pre-normalized, f32.
__global__ __launch_bounds__(256) void k_agg(const int* __restrict__ bucket,
                                             const int* __restrict__ offs,
                                             const int* __restrict__ deg,
                                             const unsigned short* __restrict__ h16,
                                             float* __restrict__ agg) {
    int t = blockIdx.x * blockDim.x + threadIdx.x;
    int node = t >> 5;
    if (node >= N_NODES) return;
    int c = t & 31;
    int dg = deg[node];
    int end = offs[node];          // post-fill value = bucket end
    int start = end - dg;
    float4 acc = {0.f, 0.f, 0.f, 0.f};
    for (int j = start; j < end; ++j) {
        int src = bucket[j];
        uint2 u = *(const uint2*)(h16 + (long long)src * D + c * 4);
        acc.x += __uint_as_float(u.x << 16);
        acc.y += __uint_as_float(u.x & 0xFFFF0000u);
        acc.z += __uint_as_float(u.y << 16);
        acc.w += __uint_as_float(u.y & 0xFFFF0000u);
    }
    float inv = 1.0f / fmaxf((float)dg, 1.0f);
    float4 o = {acc.x * inv, acc.y * inv, acc.z * inv, acc.w * inv};
    *(float4*)(agg + (long long)node * D + c * 4) = o;
}

// ---------------- kernel 5: fused dual matvec: out = agg@w_l + b_l + h@w_r ----------------
// Grid = 782 node-tiles x 2 out-channel halves = 1564 blocks of 128 threads (2 waves).
// Block: 16 ch4-lanes (64 out-ch) x 8 groups x 8 rows/thread = 64 nodes.
// Weight slab 64K x 64out staged in 16KB LDS, 4 stages (2 phases x 2 K-chunks).
// 8 FMA4 per ds_read_b128; phase-1 rows decoded from bf16 (8B loads).
// vs round 6: 2x blocks (1564), half LDS, 2-wave barriers -> better latency hiding.
#define FMA4(A, S, W) { A.x += (S)*(W).x; A.y += (S)*(W).y; A.z += (S)*(W).z; A.w += (S)*(W).w; }

__global__ __launch_bounds__(128) void k_mmf(const float* __restrict__ agg,
                                             const unsigned short* __restrict__ h16,
                                             const float* __restrict__ w_l,
                                             const float* __restrict__ w_r,
                                             const float* __restrict__ b_l,
                                             float* __restrict__ out) {
    __shared__ float4 sw4[64 * 16];          // 16 KB: 64 K-rows x 16 out-float4
    int tid = threadIdx.x;
    int ch4 = tid & 15;                      // out-channel float4 within half
    int g   = tid >> 4;                      // node group 0..7
    int tile  = blockIdx.x >> 1;
    int chalf = blockIdx.x & 1;              // which 64 output channels
    int n0 = tile * 64 + g * 8;
    int n0c = (n0 <= N_NODES - 8) ? n0 : (N_NODES - 8);   // clamp; stores guarded

    float4 acc[8];
#pragma unroll
    for (int j = 0; j < 8; ++j) acc[j] = {0.f, 0.f, 0.f, 0.f};

#pragma unroll
    for (int phase = 0; phase < 2; ++phase) {
        const float4* wsrc4 = (const float4*)(phase == 0 ? w_l : w_r);
#pragma unroll
        for (int ck = 0; ck < 2; ++ck) {
            if (phase | ck) __syncthreads();     // wait for prev consumers
            // stage 64x64 f32 weight slab (1024 float4, 8 per thread)
#pragma unroll
            for (int i = 0; i < 8; ++i) {
                int f4 = i * 128 + tid;
                int r = f4 >> 4, c4 = f4 & 15;
                sw4[f4] = wsrc4[(ck * 64 + r) * 32 + chalf * 16 + c4];
            }
            __syncthreads();

            if (phase == 0) {
                const float4* rp4 = (const float4*)(agg + (long long)n0c * D);
                for (int k0 = 0; k0 < 16; ++k0) {
                    float4 r[8];
#pragma unroll
                    for (int j = 0; j < 8; ++j) r[j] = rp4[j * 32 + ck * 16 + k0];
#pragma unroll
                    for (int kk = 0; kk < 4; ++kk) {
                        float4 wv = sw4[(k0 * 4 + kk) * 16 + ch4];
#pragma unroll
                        for (int j = 0; j < 8; ++j) {
                            float rj[4] = {r[j].x, r[j].y, r[j].z, r[j].w};
                            FMA4(acc[j], rj[kk], wv);
                        }
                    }
                }
            } else {
                const unsigned short* hp = h16 + (long long)n0c * D + ck * 64;
                for (int k0 = 0; k0 < 16; ++k0) {
                    float4 r[8];
#pragma unroll
                    for (int j = 0; j < 8; ++j) {
                        uint2 u = *(const uint2*)(hp + j * D + k0 * 4);
                        r[j].x = __uint_as_float(u.x << 16);
                        r[j].y = __uint_as_float(u.x & 0xFFFF0000u);
                        r[j].z = __uint_as_float(u.y << 16);
                        r[j].w = __uint_as_float(u.y & 0xFFFF0000u);
                    }
#pragma unroll
                    for (int kk = 0; kk < 4; ++kk) {
                        float4 wv = sw4[(k0 * 4 + kk) * 16 + ch4];
#pragma unroll
                        for (int j = 0; j < 8; ++j) {
                            float rj[4] = {r[j].x, r[j].y, r[j].z, r[j].w};
                            FMA4(acc[j], rj[kk], wv);
                        }
                    }
                }
            }
        }
    }

    float4 bl = ((const float4*)b_l)[chalf * 16 + ch4];
#pragma unroll
    for (int j = 0; j < 8; ++j) {
        int n = n0 + j;
        if (n < N_NODES) {
            float4 o = {acc[j].x + bl.x, acc[j].y + bl.y, acc[j].z + bl.z, acc[j].w + bl.w};
            *(float4*)(out + (long long)n * D + chalf * 64 + ch4 * 4) = o;
        }
    }
}

// ---------------- launcher ----------------
extern "C" void kernel_launch(void* const* d_in, const int* in_sizes, int n_in,
                              void* d_out, int out_size, void* d_ws, size_t ws_size,
                              hipStream_t stream) {
    const float* x    = (const float*)d_in[0];
    const int*   ei   = (const int*)d_in[1];
    const float* mask = (const float*)d_in[2];
    const float* lnw  = (const float*)d_in[3];
    const float* lnb  = (const float*)d_in[4];
    const float* w_l  = (const float*)d_in[5];
    const float* b_l  = (const float*)d_in[6];
    const float* w_r  = (const float*)d_in[7];
    float* out = (float*)d_out;

    char* ws = (char*)d_ws;
    double* stats = (double*)(ws + WS_STATS_OFF);
    int*    cursor= (int*)(ws + WS_CUR_OFF);
    int*    deg   = (int*)(ws + WS_DEG_OFF);
    int*    offs  = (int*)(ws + WS_OFFS_OFF);
    int*    bucket= (int*)(ws + WS_BUCKET_OFF);
    float*  agg   = (float*)(ws + WS_AGG_OFF);
    unsigned short* h16 = (unsigned short*)(ws + WS_H_OFF);

    // zero stats + cursor + deg (ws is poisoned 0xAA before every launch)
    hipMemsetAsync(d_ws, 0, WS_ZERO_BYTES, stream);

    int total4 = N_NODES * D / 4;
    k_pre<<<RED_BLOCKS + DEG_BLOCKS, 256, 0, stream>>>(x, ei, stats, deg, total4);
    k_offs<<<(N_NODES + 255) / 256, 256, 0, stream>>>(deg, offs, cursor);
    k_hfill<<<H_BLOCKS + FILL_BLOCKS, 256, 0, stream>>>(x, mask, lnw, lnb, stats,
                                                        ei, offs, bucket, h16, total4);
    int ablocks = (N_NODES * 32 + 255) / 256;   // 6250
    k_agg<<<ablocks, 256, 0, stream>>>(bucket, offs, deg, h16, agg);
    int mblocks = ((N_NODES + 63) / 64) * 2;    // 1564
    k_mmf<<<mblocks, 128, 0, stream>>>(agg, h16, w_l, w_r, b_l, out);
}

// Round 8
// 333.468 us; speedup vs baseline: 4.8442x; 1.0211x over previous
//
#include <hip/hip_runtime.h>
#include <math.h>

// GNNBlock: global-LN -> relu*dropout -> SAGE mean-aggr (CSR pull, bf16) -> dual linear via MFMA
// N=50000, E=800000, D=128
#define N_NODES 50000
#define N_EDGES 800000
#define D 128
#define EPS 1e-5f

// ---------------- workspace layout ----------------
// [0]        double sum, double sumsq        (16 B)
// [16]       int cursor                      (4 B)
// [64]       int   deg[N]                    (200000 B)
// [200192]   int   offs[N]                   (200000 B)   start; mutated to "end" by fill
// [400448]   int   bucket[E]                 (3.2 MB)     src indices grouped by dst
// [3600448]  ushort w16t[2][2][128][128]     (128 KB)     [wl/wr][hi/lo][out][k] bf16, transposed
// [3731520]  ushort agg16[N*D]               (12.8 MB)    mean aggregation, bf16
// [16531520] ushort h16[N*D]                 (12.8 MB)    h = relu(LN(x))*mask, bf16
#define WS_STATS_OFF   0
#define WS_CUR_OFF     16
#define WS_DEG_OFF     64
#define WS_OFFS_OFF    200192
#define WS_BUCKET_OFF  400448
#define WS_W16T_OFF    3600448
#define WS_AGG_OFF     3731520
#define WS_H_OFF       16531520
#define WS_ZERO_BYTES  200192     // stats + cursor + deg

#define RED_BLOCKS 1024
#define DEG_BLOCKS ((N_EDGES + 255) / 256)   // 3125
#define H_BLOCKS   2048
#define FILL_BLOCKS DEG_BLOCKS

typedef __attribute__((ext_vector_type(8))) short short8v;   // 8 bf16 = 4 VGPR (MFMA A/B frag)
typedef __attribute__((ext_vector_type(4))) float f32x4;     // MFMA C/D frag

// bf16 helpers (RNE encode, shift decode)
static __device__ inline unsigned short f2bf(float f) {
    unsigned u = __float_as_uint(f);
    return (unsigned short)((u + 0x7FFFu + ((u >> 16) & 1u)) >> 16);
}
static __device__ inline float bf2f(unsigned short s) {
    return __uint_as_float(((unsigned)s) << 16);
}

// ---------------- kernel 1: global sum/sumsq + degree histogram (fused, independent) ----------------
__global__ __launch_bounds__(256) void k_pre(const float* __restrict__ x,
                                             const int* __restrict__ ei,
                                             double* __restrict__ stats,
                                             int* __restrict__ deg,
                                             int total4) {
    __shared__ float bs[4], bss[4];
    if (blockIdx.x < RED_BLOCKS) {
        int tid = blockIdx.x * 256 + threadIdx.x;
        int stride = RED_BLOCKS * 256;
        float s = 0.f, ss = 0.f;
        for (int i = tid; i < total4; i += stride) {
            float4 v = ((const float4*)x)[i];
            s  += v.x + v.y + v.z + v.w;
            ss += v.x*v.x + v.y*v.y + v.z*v.z + v.w*v.w;
        }
        for (int off = 32; off; off >>= 1) {
            s  += __shfl_down(s, off);
            ss += __shfl_down(ss, off);
        }
        int lane = threadIdx.x & 63, wid = threadIdx.x >> 6;
        if (lane == 0) { bs[wid] = s; bss[wid] = ss; }
        __syncthreads();
        if (threadIdx.x == 0) {
            float t = 0.f, tt = 0.f;
            for (int w = 0; w < 4; ++w) { t += bs[w]; tt += bss[w]; }
            atomicAdd(stats, (double)t);
            atomicAdd(stats + 1, (double)tt);
        }
    } else {
        int e = (blockIdx.x - RED_BLOCKS) * 256 + threadIdx.x;
        if (e < N_EDGES) atomicAdd(deg + ei[N_EDGES + e], 1);
    }
}

// ---------------- kernel 1b: weight prep — transpose + hi/lo bf16 split ----------------
// w16t[p][s][o][k]: s=0 hi=bf16(w), s=1 lo=bf16(w - hi). A@(hi+lo) ~= A@w at f32 weight precision.
__global__ __launch_bounds__(256) void k_wprep(const float* __restrict__ w_l,
                                               const float* __restrict__ w_r,
                                               unsigned short* __restrict__ w16t) {
    int t = blockIdx.x * 256 + threadIdx.x;          // 8192 threads: [p][o][k4]
    int p = t >> 12;
    int o = (t >> 5) & 127;
    int k4 = t & 31;
    const float* w = p ? w_r : w_l;
    ushort4 hi, lo;
    float v0 = w[(k4 * 4 + 0) * D + o];
    float v1 = w[(k4 * 4 + 1) * D + o];
    float v2 = w[(k4 * 4 + 2) * D + o];
    float v3 = w[(k4 * 4 + 3) * D + o];
    hi.x = f2bf(v0); lo.x = f2bf(v0 - bf2f(hi.x));
    hi.y = f2bf(v1); lo.y = f2bf(v1 - bf2f(hi.y));
    hi.z = f2bf(v2); lo.z = f2bf(v2 - bf2f(hi.z));
    hi.w = f2bf(v3); lo.w = f2bf(v3 - bf2f(hi.w));
    *(ushort4*)(w16t + p * 32768 + o * D + k4 * 4) = hi;
    *(ushort4*)(w16t + p * 32768 + 16384 + o * D + k4 * 4) = lo;
}

// ---------------- kernel 2: bucket-region assignment (block scan + global cursor) ----------------
__global__ __launch_bounds__(256) void k_offs(const int* __restrict__ deg,
                                              int* __restrict__ offs,
                                              int* __restrict__ cursor) {
    __shared__ int sc[256];
    __shared__ int sbase;
    int t = threadIdx.x;
    int n = blockIdx.x * 256 + t;
    int d = (n < N_NODES) ? deg[n] : 0;
    sc[t] = d;
    __syncthreads();
    for (int off = 1; off < 256; off <<= 1) {   // inclusive Hillis-Steele scan
        int u = (t >= off) ? sc[t - off] : 0;
        __syncthreads();
        sc[t] += u;
        __syncthreads();
    }
    int incl = sc[t];
    if (t == 255) sbase = atomicAdd(cursor, incl);
    __syncthreads();
    if (n < N_NODES) offs[n] = sbase + (incl - d);
}

// ---------------- kernel 3: h16 = bf16(relu(LN(x))*mask)  +  bucket fill (fused) ----------------
__global__ __launch_bounds__(256) void k_hfill(const float* __restrict__ x,
                                               const float* __restrict__ mask,
                                               const float* __restrict__ lnw,
                                               const float* __restrict__ lnb,
                                               const double* __restrict__ stats,
                                               const int* __restrict__ ei,
                                               int* __restrict__ offs,
                                               int* __restrict__ bucket,
                                               unsigned short* __restrict__ h16,
                                               int total4) {
    if (blockIdx.x < H_BLOCKS) {
        double M = (double)N_NODES * (double)D;
        double mean_d = stats[0] / M;
        double var = stats[1] / M - mean_d * mean_d;
        if (var < 0.0) var = 0.0;
        float mean = (float)mean_d;
        float rstd = (float)(1.0 / (sqrt(var) + (double)EPS));
        int tid = blockIdx.x * 256 + threadIdx.x;
        int stride = H_BLOCKS * 256;
        for (int i = tid; i < total4; i += stride) {
            float4 v = ((const float4*)x)[i];
            float4 m = ((const float4*)mask)[i];
            int c4 = i & (D / 4 - 1);
            float4 w = ((const float4*)lnw)[c4];
            float4 b = ((const float4*)lnb)[c4];
            float4 r;
            r.x = fmaxf((v.x - mean) * rstd * w.x + b.x, 0.f) * m.x;
            r.y = fmaxf((v.y - mean) * rstd * w.y + b.y, 0.f) * m.y;
            r.z = fmaxf((v.z - mean) * rstd * w.z + b.z, 0.f) * m.z;
            r.w = fmaxf((v.w - mean) * rstd * w.w + b.w, 0.f) * m.w;
            ushort4 o;
            o.x = f2bf(r.x); o.y = f2bf(r.y); o.z = f2bf(r.z); o.w = f2bf(r.w);
            ((ushort4*)h16)[i] = o;
        }
    } else {
        int e = (blockIdx.x - H_BLOCKS) * 256 + threadIdx.x;
        if (e < N_EDGES) {
            int dst = ei[N_EDGES + e];
            int p = atomicAdd(offs + dst, 1);
            bucket[p] = ei[e];
        }
    }
}

// ---------------- kernel 4: pull aggregation (atomic-free, bf16 in/out) ----------------
// 32 lanes per dst node, 4 bf16 channels (8B) per lane; f32 accumulate, bf16 store.
__global__ __launch_bounds__(256) void k_agg(const int* __restrict__ bucket,
                                             const int* __restrict__ offs,
                                             const int* __restrict__ deg,
                                             const unsigned short* __restrict__ h16,
                                             unsigned short* __restrict__ agg16) {
    int t = blockIdx.x * blockDim.x + threadIdx.x;
    int node = t >> 5;
    if (node >= N_NODES) return;
    int c = t & 31;
    int dg = deg[node];
    int end = offs[node];          // post-fill value = bucket end
    int start = end - dg;
    float4 acc = {0.f, 0.f, 0.f, 0.f};
    for (int j = start; j < end; ++j) {
        int src = bucket[j];
        uint2 u = *(const uint2*)(h16 + (long long)src * D + c * 4);
        acc.x += __uint_as_float(u.x << 16);
        acc.y += __uint_as_float(u.x & 0xFFFF0000u);
        acc.z += __uint_as_float(u.y << 16);
        acc.w += __uint_as_float(u.y & 0xFFFF0000u);
    }
    float inv = 1.0f / fmaxf((float)dg, 1.0f);
    ushort4 o;
    o.x = f2bf(acc.x * inv); o.y = f2bf(acc.y * inv);
    o.z = f2bf(acc.z * inv); o.w = f2bf(acc.w * inv);
    *(ushort4*)(agg16 + (long long)node * D + c * 4) = o;
}

// ---------------- kernel 5: MFMA dual matvec: out = agg@w_l + b_l + h@w_r ----------------
// One wave per 16-node x 16-out tile: 25000 waves (3125 node-tiles x 8 out-tiles),
// 6250 blocks x 256. No LDS; A/B frags loaded straight from global (16B/lane,
// L2-resident). 16 MFMA/wave: 2 operands x {hi,lo} x K=128. All acc into one
// f32x4 frag. A-frag: row=lane&15, k=(lane>>4)*8+j from row-major [M][128] bf16.
// B-frag: col=lane&15, same k mapping, from w16t[out][k]. D: col=lane&15,
// row=(lane>>4)*4+r (m89-verified).
__global__ __launch_bounds__(256) void k_mmf(const unsigned short* __restrict__ agg16,
                                             const unsigned short* __restrict__ h16,
                                             const unsigned short* __restrict__ w16t,
                                             const float* __restrict__ b_l,
                                             float* __restrict__ out) {
    int wid = (blockIdx.x << 2) | (threadIdx.x >> 6);   // global wave id, 0..24999
    int lane = threadIdx.x & 63;
    int nt = wid >> 3;          // node tile 0..3124  (50000/16 == 3125 exactly)
    int ot = wid & 7;           // out tile 0..7
    int rc = lane & 15;         // A-row / B-col / D-col
    int kg = lane >> 4;         // k-group 0..3

    const unsigned short* pa = agg16 + ((long long)(nt * 16 + rc)) * D + kg * 8;
    const unsigned short* ph = h16   + ((long long)(nt * 16 + rc)) * D + kg * 8;
    const unsigned short* bl_hi = w16t + (ot * 16 + rc) * D + kg * 8;            // w_l hi
    const unsigned short* bl_lo = bl_hi + 16384;                                  // w_l lo
    const unsigned short* br_hi = bl_hi + 32768;                                  // w_r hi
    const unsigned short* br_lo = bl_hi + 49152;                                  // w_r lo

    f32x4 acc = {0.f, 0.f, 0.f, 0.f};
#pragma unroll
    for (int k0 = 0; k0 < 4; ++k0) {
        short8v a = *(const short8v*)(pa + k0 * 32);
        acc = __builtin_amdgcn_mfma_f32_16x16x32_bf16(a, *(const short8v*)(bl_hi + k0 * 32), acc, 0, 0, 0);
        acc = __builtin_amdgcn_mfma_f32_16x16x32_bf16(a, *(const short8v*)(bl_lo + k0 * 32), acc, 0, 0, 0);
    }
#pragma unroll
    for (int k0 = 0; k0 < 4; ++k0) {
        short8v a = *(const short8v*)(ph + k0 * 32);
        acc = __builtin_amdgcn_mfma_f32_16x16x32_bf16(a, *(const short8v*)(br_hi + k0 * 32), acc, 0, 0, 0);
        acc = __builtin_amdgcn_mfma_f32_16x16x32_bf16(a, *(const short8v*)(br_lo + k0 * 32), acc, 0, 0, 0);
    }

    float bias = b_l[ot * 16 + rc];
    float* op = out + ((long long)(nt * 16 + kg * 4)) * D + ot * 16 + rc;
#pragma unroll
    for (int r = 0; r < 4; ++r)
        op[(long long)r * D] = acc[r] + bias;
}

// ---------------- launcher ----------------
extern "C" void kernel_launch(void* const* d_in, const int* in_sizes, int n_in,
                              void* d_out, int out_size, void* d_ws, size_t ws_size,
                              hipStream_t stream) {
    const float* x    = (const float*)d_in[0];
    const int*   ei   = (const int*)d_in[1];
    const float* mask = (const float*)d_in[2];
    const float* lnw  = (const float*)d_in[3];
    const float* lnb  = (const float*)d_in[4];
    const float* w_l  = (const float*)d_in[5];
    const float* b_l  = (const float*)d_in[6];
    const float* w_r  = (const float*)d_in[7];
    float* out = (float*)d_out;

    char* ws = (char*)d_ws;
    double* stats = (double*)(ws + WS_STATS_OFF);
    int*    cursor= (int*)(ws + WS_CUR_OFF);
    int*    deg   = (int*)(ws + WS_DEG_OFF);
    int*    offs  = (int*)(ws + WS_OFFS_OFF);
    int*    bucket= (int*)(ws + WS_BUCKET_OFF);
    unsigned short* w16t  = (unsigned short*)(ws + WS_W16T_OFF);
    unsigned short* agg16 = (unsigned short*)(ws + WS_AGG_OFF);
    unsigned short* h16   = (unsigned short*)(ws + WS_H_OFF);

    // zero stats + cursor + deg (ws is poisoned 0xAA before every launch)
    hipMemsetAsync(d_ws, 0, WS_ZERO_BYTES, stream);

    int total4 = N_NODES * D / 4;
    k_pre<<<RED_BLOCKS + DEG_BLOCKS, 256, 0, stream>>>(x, ei, stats, deg, total4);
    k_wprep<<<32, 256, 0, stream>>>(w_l, w_r, w16t);
    k_offs<<<(N_NODES + 255) / 256, 256, 0, stream>>>(deg, offs, cursor);
    k_hfill<<<H_BLOCKS + FILL_BLOCKS, 256, 0, stream>>>(x, mask, lnw, lnb, stats,
                                                        ei, offs, bucket, h16, total4);
    int ablocks = (N_NODES * 32 + 255) / 256;   // 6250
    k_agg<<<ablocks, 256, 0, stream>>>(bucket, offs, deg, h16, agg16);
    int mblocks = (N_NODES / 16) * 8 / 4;       // 6250 blocks = 25000 waves
    k_mmf<<<mblocks, 256, 0, stream>>>(agg16, h16, w16t, b_l, out);
}